// Round 1
// baseline (15811.885 us; speedup 1.0000x reference)
//
#include <hip/hip_runtime.h>
#include <stdint.h>

// Problem constants (from reference)
#define MA   50            // MAX_ATOMS
#define NGF  30            // N_GRAPH_FEAT
#define NAF  75            // N_ATOM_FEAT
#define NA   6400          // N_ATOMS = 50*128
#define H    100           // HIDDEN
#define NIN  1545          // 75 + 49*30
#define GFS  51            // gf slots per row (MAX_ATOMS+1)
#define RPB  8             // rows per block

// gf state: NA * GFS * NGF floats = 39,168,000 bytes, lives at d_ws[0]
#define GF_ELEMS ((size_t)NA * GFS * NGF)

__global__ void zero_gf(float* __restrict__ gf, int n) {
    int i = blockIdx.x * blockDim.x + threadIdx.x;
    int stride = gridDim.x * blockDim.x;
    for (; i < n; i += stride) gf[i] = 0.0f;
}

// Detect whether calculation_masks arrived as 1-byte bools or int32.
// int32 0/1 data has all bytes at pos%4!=0 equal to 0; 1-byte bools (~50% ones) don't.
__global__ void detect_mask(const uint8_t* __restrict__ cm, int* __restrict__ flag) {
    if (threadIdx.x == 0 && blockIdx.x == 0) {
        int f = 0;
        for (int pos = 1; pos < 4096; ++pos) {
            if ((pos & 3) != 0 && cm[pos] != 0) { f = 1; break; }
        }
        *flag = f;   // 1 => bool (1 byte/elem), 0 => int32
    }
}

__global__ __launch_bounds__(128) void dag_step(
    const float* __restrict__ af,      // (NA, NAF)
    const int*   __restrict__ parents, // (NA, MA, MA)
    const int*   __restrict__ orders,  // (NA, MA)
    const void*  __restrict__ cmask,   // (NA, MA) bool-or-int32
    const float* __restrict__ W0,      // (NIN, H)
    const float* __restrict__ b0,      // (H)
    const float* __restrict__ W1,      // (H, NGF)
    const float* __restrict__ b1,      // (NGF)
    float*       __restrict__ gf,      // (NA, GFS, NGF) state
    const int*   __restrict__ flagp,
    float*       __restrict__ dout,    // (NA, NGF)
    int t)
{
    __shared__ float xs[RPB][NIN];   // 49,440 B
    __shared__ float hs[RPB][H];     //  3,200 B
    __shared__ int   colc[RPB];
    __shared__ int   maskc[RPB];

    const int tid  = threadIdx.x;
    const int row0 = blockIdx.x * RPB;
    const int flag = *flagp;

    // ---- Phase 1: gather x for RPB rows ----
    for (int r = 0; r < RPB; ++r) {
        const int i = row0 + r;
        const int* par = parents + ((long)i * MA + t) * MA;
        const int order = orders[i * MA + t];
        const float* gfr = gf + (long)i * GFS * NGF;
        const float* afr = af + (long)order * NAF;
        for (int k = tid; k < NIN; k += 128) {
            float v;
            if (k < NAF) {
                v = afr[k];
            } else {
                int kk = k - NAF;
                int p  = kk / NGF;          // 0..48
                int c  = kk - p * NGF;      // 0..29
                int slot = par[1 + p];      // 0..50
                v = gfr[slot * NGF + c];
            }
            xs[r][k] = v;
        }
        if (tid == 0) {
            colc[r] = par[0];
            int m;
            if (flag) m = (((const uint8_t*)cmask)[i * MA + t] != 0);
            else      m = (((const int*)cmask)[i * MA + t] != 0);
            maskc[r] = m;
        }
    }
    __syncthreads();

    // ---- Phase 2: h = relu(x @ W0 + b0), thread j owns column j ----
    const int j = tid;
    if (j < H) {
        float acc[RPB];
        const float bj = b0[j];
        #pragma unroll
        for (int r = 0; r < RPB; ++r) acc[r] = bj;
        const float* w0p = W0 + j;
        #pragma unroll 8
        for (int k = 0; k < NIN; ++k) {
            float w = w0p[(long)k * H];
            #pragma unroll
            for (int r = 0; r < RPB; ++r)
                acc[r] = fmaf(xs[r][k], w, acc[r]);
        }
        #pragma unroll
        for (int r = 0; r < RPB; ++r) hs[r][j] = fmaxf(acc[r], 0.0f);
    }
    __syncthreads();

    // ---- Phase 3: out = relu(h @ W1 + b1); masked scatter into gf; final output at t==MA-1 ----
    for (int o = tid; o < RPB * NGF; o += 128) {
        const int r  = o / NGF;
        const int j2 = o - r * NGF;
        const int i  = row0 + r;
        float a = b1[j2];
        #pragma unroll 4
        for (int k = 0; k < H; ++k)
            a = fmaf(hs[r][k], W1[k * NGF + j2], a);
        a = fmaxf(a, 0.0f);
        const int m = maskc[r];
        if (m) gf[((long)i * GFS + colc[r]) * NGF + j2] = a;
        if (t == MA - 1) dout[i * NGF + j2] = m ? a : 0.0f;
    }
}

extern "C" void kernel_launch(void* const* d_in, const int* in_sizes, int n_in,
                              void* d_out, int out_size, void* d_ws, size_t ws_size,
                              hipStream_t stream) {
    const float* af      = (const float*)d_in[0];
    const int*   parents = (const int*)  d_in[1];
    const int*   orders  = (const int*)  d_in[2];
    const void*  cmask   =               d_in[3];
    // d_in[4] = n_atoms scalar (fixed 6400), unused
    const float* W0      = (const float*)d_in[5];
    const float* b0      = (const float*)d_in[6];
    const float* W1      = (const float*)d_in[7];
    const float* b1      = (const float*)d_in[8];

    float* gf    = (float*)d_ws;
    int*   flagp = (int*)((char*)d_ws + GF_ELEMS * sizeof(float));
    float* dout  = (float*)d_out;

    zero_gf<<<2048, 256, 0, stream>>>(gf, (int)GF_ELEMS);
    detect_mask<<<1, 64, 0, stream>>>((const uint8_t*)cmask, flagp);

    for (int t = 0; t < MA; ++t) {
        dag_step<<<NA / RPB, 128, 0, stream>>>(
            af, parents, orders, cmask, W0, b0, W1, b1, gf, flagp, dout, t);
    }
}

// Round 2
// 5753.826 us; speedup vs baseline: 2.7481x; 2.7481x over previous
//
#include <hip/hip_runtime.h>
#include <stdint.h>

// Problem constants (from reference)
#define MA   50            // MAX_ATOMS
#define NGF  30            // N_GRAPH_FEAT
#define NAF  75            // N_ATOM_FEAT
#define NA   6400          // N_ATOMS = 50*128
#define H    100           // HIDDEN
#define NIN  1545          // 75 + 49*30
#define GFS  51            // gf slots per row (MAX_ATOMS+1)
#define RPB  8             // rows per block
#define NTHR 512           // threads per block (8 waves)

// Detect whether calculation_masks arrived as 1-byte bools or int32.
// int32 0/1 data has all bytes at pos%4!=0 equal to 0; 1-byte bools (~50% ones) don't.
__global__ void detect_mask(const uint8_t* __restrict__ cm, int* __restrict__ flag) {
    if (threadIdx.x == 0 && blockIdx.x == 0) {
        int f = 0;
        for (int pos = 1; pos < 4096; ++pos) {
            if ((pos & 3) != 0 && cm[pos] != 0) { f = 1; break; }
        }
        *flag = f;   // 1 => bool (1 byte/elem), 0 => int32
    }
}

// One block owns RPB rows for the entire 50-step recurrence; gf state lives in LDS.
__global__ __launch_bounds__(NTHR, 4) void dag_fused(
    const float* __restrict__ af,      // (NA, NAF)
    const int*   __restrict__ parents, // (NA, MA, MA)
    const int*   __restrict__ orders,  // (NA, MA)
    const void*  __restrict__ cmask,   // (NA, MA) bool-or-int32
    const float* __restrict__ W0,      // (NIN, H)
    const float* __restrict__ b0,      // (H)
    const float* __restrict__ W1,      // (H, NGF)
    const float* __restrict__ b1,      // (NGF)
    const int*   __restrict__ flagp,
    float*       __restrict__ dout)    // (NA, NGF)
{
    __shared__ float gfl[RPB][GFS * NGF];   // 48,960 B — per-row DAG state
    __shared__ float afx[RPB][NAF];         //  2,400 B — atom-feature part of x
    __shared__ int   slots[RPB][MA - 1];    //  1,568 B — parent slots 1..49
    __shared__ int   colc[RPB];
    __shared__ int   maskc[RPB];
    __shared__ float partial[2][RPB][H];    //  6,400 B — K-split reduction
    __shared__ float hs[RPB][H];            //  3,200 B — hidden activations
    // total ~62.6 KB -> 2 blocks/CU, 16 waves/CU

    const int tid  = threadIdx.x;
    const int row0 = blockIdx.x * RPB;
    const int flag = *flagp;
    const int ks   = tid >> 7;     // 0..3  K-segment (wave-uniform)
    const int j    = tid & 127;    // 0..127 hidden column (active j<100)

    // zero gf state (== reference gf0)
    for (int e = tid; e < RPB * GFS * NGF; e += NTHR) (&gfl[0][0])[e] = 0.0f;

    for (int t = 0; t < MA; ++t) {
        // ---- gather: af part, parent slots, col/mask ----
        for (int e = tid; e < RPB * NAF; e += NTHR) {
            int r = e / NAF, k = e - r * NAF;
            int order = orders[(row0 + r) * MA + t];
            afx[r][k] = af[(long)order * NAF + k];
        }
        for (int e = tid; e < RPB * (MA - 1); e += NTHR) {
            int r = e / (MA - 1), p = e - r * (MA - 1);
            slots[r][p] = parents[((long)(row0 + r) * MA + t) * MA + 1 + p];
        }
        if (tid < RPB) {
            int i = row0 + tid;
            colc[tid] = parents[((long)i * MA + t) * MA];
            int m;
            if (flag) m = ((const uint8_t*)cmask)[i * MA + t] != 0;
            else      m = ((const int*)  cmask)[i * MA + t] != 0;
            maskc[tid] = m;
        }
        __syncthreads();

        // ---- phase 2: h = x @ W0, 4-way K-split, thread (ks, j) does 8 rows ----
        float acc[RPB];
        #pragma unroll
        for (int r = 0; r < RPB; ++r) acc[r] = 0.0f;

        if (j < H) {
            const float* W0j = W0 + j;
            if (ks == 0) {
                // atom-feature part: k = 0..74
                #pragma unroll 5
                for (int k = 0; k < NAF; ++k) {
                    float w = W0j[k * H];
                    #pragma unroll
                    for (int r = 0; r < RPB; ++r) acc[r] = fmaf(afx[r][k], w, acc[r]);
                }
            }
            const int p0 = (ks == 0) ? 0  : 10 + (ks - 1) * 13;
            const int p1 = (ks == 0) ? 10 : p0 + 13;
            for (int p = p0; p < p1; ++p) {
                const float* base[RPB];
                #pragma unroll
                for (int r = 0; r < RPB; ++r) base[r] = &gfl[r][slots[r][p] * NGF];
                const float* wp = W0j + (NAF + p * NGF) * H;
                #pragma unroll 5
                for (int cc = 0; cc < NGF; cc += 2) {
                    float w0 = wp[cc * H];
                    float w1 = wp[(cc + 1) * H];
                    #pragma unroll
                    for (int r = 0; r < RPB; ++r) {
                        float2 xv = *(const float2*)(base[r] + cc);
                        acc[r] = fmaf(xv.x, w0, acc[r]);
                        acc[r] = fmaf(xv.y, w1, acc[r]);
                    }
                }
            }
        }

        // ---- tree-reduce the 4 K-partials ----
        if (ks >= 2 && j < H) {
            #pragma unroll
            for (int r = 0; r < RPB; ++r) partial[ks - 2][r][j] = acc[r];
        }
        __syncthreads();
        if (ks < 2 && j < H) {
            #pragma unroll
            for (int r = 0; r < RPB; ++r) acc[r] += partial[ks][r][j];
        }
        __syncthreads();
        if (ks == 1 && j < H) {
            #pragma unroll
            for (int r = 0; r < RPB; ++r) partial[0][r][j] = acc[r];
        }
        __syncthreads();
        if (ks == 0 && j < H) {
            float bj = b0[j];
            #pragma unroll
            for (int r = 0; r < RPB; ++r)
                hs[r][j] = fmaxf(acc[r] + partial[0][r][j] + bj, 0.0f);
        }
        __syncthreads();

        // ---- phase 3: out = relu(h @ W1 + b1); masked scatter into LDS gf ----
        for (int o = tid; o < RPB * NGF; o += NTHR) {
            int r = o / NGF, j2 = o - r * NGF;
            float a = b1[j2];
            #pragma unroll 4
            for (int k = 0; k < H; ++k) a = fmaf(hs[r][k], W1[k * NGF + j2], a);
            a = fmaxf(a, 0.0f);
            if (maskc[r]) gfl[r][colc[r] * NGF + j2] = a;
            if (t == MA - 1) dout[(row0 + r) * NGF + j2] = maskc[r] ? a : 0.0f;
        }
        __syncthreads();   // protect colc/maskc/gfl before next step's gather
    }
}

extern "C" void kernel_launch(void* const* d_in, const int* in_sizes, int n_in,
                              void* d_out, int out_size, void* d_ws, size_t ws_size,
                              hipStream_t stream) {
    const float* af      = (const float*)d_in[0];
    const int*   parents = (const int*)  d_in[1];
    const int*   orders  = (const int*)  d_in[2];
    const void*  cmask   =               d_in[3];
    // d_in[4] = n_atoms scalar (fixed 6400), unused
    const float* W0      = (const float*)d_in[5];
    const float* b0      = (const float*)d_in[6];
    const float* W1      = (const float*)d_in[7];
    const float* b1      = (const float*)d_in[8];

    int*   flagp = (int*)d_ws;
    float* dout  = (float*)d_out;

    detect_mask<<<1, 64, 0, stream>>>((const uint8_t*)cmask, flagp);
    dag_fused<<<NA / RPB, NTHR, 0, stream>>>(
        af, parents, orders, cmask, W0, b0, W1, b1, flagp, dout);
}